// Round 11
// baseline (753.755 us; speedup 1.0000x reference)
//
#include <hip/hip_runtime.h>
#include <stdint.h>

typedef float v4f __attribute__((ext_vector_type(4)));
typedef float v2f __attribute__((ext_vector_type(2)));
typedef short bf16x8 __attribute__((ext_vector_type(8)));
typedef int v4i __attribute__((ext_vector_type(4)));
typedef int v8i __attribute__((ext_vector_type(8)));
typedef unsigned int uint32;
typedef unsigned long long u64;

#define V_N 30000
#define E_N 300
#define EPAD 320
#define H_N 256
#define G_N 1024
#define B_N 64
#define S_N 512
#define T_N 9

// workspace layout (bytes)
#define OFF_EMB  ((size_t)0)            // [V][320] bf16          19,200,000
#define OFF_WIH  ((size_t)19200000)     // [2][1024][320] bf16     1,310,720
#define OFF_WHH  ((size_t)20510720)     // [2][8][8][2][64][32B]     524,288
#define OFF_PRE  ((size_t)21035008)     // [2][t512][bg4][qp8][w8][n16][tt8]4B = 134,217,728
#define OFF_H    ((size_t)155252736)    // [64][512][512] f32      67,108,864

__device__ __forceinline__ uint32 bf16r(float x){
  uint32 u = __float_as_uint(x);
  u += 0x7FFFu + ((u>>16)&1u);
  return u>>16;
}
__device__ __forceinline__ float sigm(float x){
  return __builtin_amdgcn_rcpf(1.f + __builtin_amdgcn_exp2f(-1.4426950408889634f*x));
}
__device__ __forceinline__ float tanh_(float x){
  return 1.f - 2.f*__builtin_amdgcn_rcpf(1.f + __builtin_amdgcn_exp2f(2.8853900817779268f*x));
}
__device__ __forceinline__ void gld16(const void* g, void* l){
  __builtin_amdgcn_global_load_lds(
    (const __attribute__((address_space(1))) void*)g,
    (__attribute__((address_space(3))) void*)l, 16, 0, 0);
}
__device__ __forceinline__ float rdlane(float x, int l){
  return __uint_as_float(__builtin_amdgcn_readlane(__float_as_uint(x), l));
}

// ---------------- prep (fused): out[0]=0, emb+Wih -> bf16 pad320, Whh -> fp8 ----------------
__global__ void k_prep(const float* __restrict__ emb,
                       const float* __restrict__ wih_f,
                       const float* __restrict__ wih_b,
                       const float* __restrict__ whh_f,
                       const float* __restrict__ whh_b,
                       char* __restrict__ ws,
                       float* __restrict__ out){
  int tid = blockIdx.x*256 + threadIdx.x;
  if (tid == 0) out[0] = 0.f;
  // ---- Whh -> fp8 e4m3 (x64) in 16x16x128 B-operand layout (first 65536 threads) ----
  if (tid < 65536){
    int part = tid&3;
    int lane = (tid>>2)&63;
    int kk = (tid>>8)&1, tt = (tid>>9)&7, w = (tid>>12)&7, dir = (tid>>15)&1;
    const float* W = dir? whh_b : whh_f;
    int n = lane&15, lq = lane>>4;
    int col = (tt>>1)*256 + w*32 + (tt&1)*16 + n;   // gate*256 + unit
    int k0  = kk*128 + lq*32 + part*8;
    const float* p = W + (size_t)col*H_N + k0;
    int lo = __builtin_amdgcn_cvt_pk_fp8_f32(p[0]*64.f, p[1]*64.f, 0, false);
    lo = __builtin_amdgcn_cvt_pk_fp8_f32(p[2]*64.f, p[3]*64.f, lo, true);
    int hi = __builtin_amdgcn_cvt_pk_fp8_f32(p[4]*64.f, p[5]*64.f, 0, false);
    hi = __builtin_amdgcn_cvt_pk_fp8_f32(p[6]*64.f, p[7]*64.f, hi, true);
    u64 v = (uint32)lo | ((u64)(uint32)hi<<32);
    ((u64*)(ws+OFF_WHH))[tid] = v;
  }
  // ---- emb + Wih -> bf16 padded to K=320 ----
  const int NE = V_N*40;
  unsigned short* eo = (unsigned short*)(ws + OFF_EMB);
  unsigned short* wo = (unsigned short*)(ws + OFF_WIH);
  const float* src; unsigned short* dst; int g;
  if (tid < NE){
    int row = tid/40; g = tid%40;
    src = emb + (size_t)row*E_N;
    dst = eo + (size_t)row*EPAD + g*8;
  } else if (tid < NE + 2*G_N*40){
    int t2 = tid - NE;
    int dir = t2/(G_N*40); int r2 = t2%(G_N*40);
    int row = r2/40; g = r2%40;
    src = (dir? wih_b : wih_f) + (size_t)row*E_N;
    dst = wo + ((size_t)dir*G_N + row)*EPAD + g*8;
  } else return;
  unsigned short v[8];
  #pragma unroll
  for (int j=0;j<8;j++){
    int c = g*8+j;
    float x = (c < E_N)? src[c] : 0.f;
    v[j] = (unsigned short)bf16r(x);
  }
  uint4 pk;
  pk.x = (uint32)v[0] | ((uint32)v[1]<<16);
  pk.y = (uint32)v[2] | ((uint32)v[3]<<16);
  pk.z = (uint32)v[4] | ((uint32)v[5]<<16);
  pk.w = (uint32)v[6] | ((uint32)v[7]<<16);
  *(uint4*)dst = pk;
}

// ---------------- input projection: pre = emb[ids] @ Wih^T + bias (bf16 MFMA) -------------
// global_load_lds double-buffered staging; counted vmcnt(4); raw s_barrier (no vmcnt drain).
// Block nc covers lstm w_l = nc: B rows c(r) = (r>>5)*256 + nc*32 + (r&31) so tile nt == tt.
// Epilogue: each lane stores 32B-contiguous tt runs -> 256B-coalesced segments per q-group.
__global__ __launch_bounds__(256,2)
void k_gemm1(const int* __restrict__ ids, char* __restrict__ ws,
             const float* __restrict__ bih_f, const float* __restrict__ bhh_f,
             const float* __restrict__ bih_b, const float* __restrict__ bhh_b){
  int bx = blockIdx.x;                      // [dir(2)][tp(256)][nc(8)]
  int nc = bx & 7, tp = (bx>>3)&255, dir = bx>>11;
  const char* embB = (const char*)(ws+OFF_EMB);
  const char* wihB = (const char*)(ws+OFF_WIH) + (size_t)dir*G_N*EPAD*2;
  __shared__ unsigned short Asl[2][128*32];
  __shared__ unsigned short Bsl[2][128*32];
  __shared__ int ids_s[128];
  int tid = threadIdx.x, lane = tid&63, w = tid>>6;
  if (tid < 128){
    int t = tp*2 + (tid>>6), b = tid&63;
    ids_s[tid] = ids[b*S_N + t];
  }
  __syncthreads();
  v4f acc[2][8];
  #pragma unroll
  for (int i=0;i<2;i++)
    #pragma unroll
    for (int j=0;j<8;j++) acc[i][j] = (v4f){0.f,0.f,0.f,0.f};
  int n0 = lane&15, q = lane>>4;
  // per-wave staging rows: wave w covers local row blocks [w*16,..) and [(w+4)*16,..)
  int rA0 = w*16 + (lane>>2), rA1 = (w+4)*16 + (lane>>2);
  int ch = (lane&3)*16;                      // byte chunk within a 64B row-slice
  long idA0 = ids_s[rA0], idA1 = ids_s[rA1];
  const char* gA0 = embB + idA0*640 + ch;
  const char* gA1 = embB + idA1*640 + ch;
  // B local row r -> global unit row c(r) = (r>>5)*256 + nc*32 + (r&31)
  int cB0 = ((rA0>>5)<<8) + nc*32 + (rA0&31);
  int cB1 = ((rA1>>5)<<8) + nc*32 + (rA1&31);
  const char* gB0 = wihB + (size_t)cB0*640 + ch;
  const char* gB1 = wihB + (size_t)cB1*640 + ch;
  const float* bi = dir? bih_b : bih_f;
  const float* bh = dir? bhh_b : bhh_f;
  float bv[8];
  #pragma unroll
  for (int nt=0; nt<8; nt++){
    int c = ((nt>>1)<<8) + nc*32 + ((nt&1)<<4) + n0;   // unit col for tile nt (== tt)
    bv[nt] = bi[c] + bh[c];
  }
  // drain bias/ids loads so loop vmcnt counting is exact
  asm volatile("s_waitcnt vmcnt(0)" ::: "memory");
  // prologue stage: ks=0 into buffer 0
  {
    gld16(gA0, (char*)Asl[0] + (size_t)w*1024);
    gld16(gA1, (char*)Asl[0] + (size_t)(w+4)*1024);
    gld16(gB0, (char*)Bsl[0] + (size_t)w*1024);
    gld16(gB1, (char*)Bsl[0] + (size_t)(w+4)*1024);
  }
  for (int ks=0; ks<10; ks++){
    int cur = ks&1;
    if (ks < 9){
      int ko = (ks+1)*64;
      gld16(gA0 + ko, (char*)Asl[cur^1] + (size_t)w*1024);
      gld16(gA1 + ko, (char*)Asl[cur^1] + (size_t)(w+4)*1024);
      gld16(gB0 + ko, (char*)Bsl[cur^1] + (size_t)w*1024);
      gld16(gB1 + ko, (char*)Bsl[cur^1] + (size_t)(w+4)*1024);
      asm volatile("s_waitcnt vmcnt(4)" ::: "memory");
    } else {
      asm volatile("s_waitcnt vmcnt(0)" ::: "memory");
    }
    __builtin_amdgcn_s_barrier();
    bf16x8 bfr[8], afr[2];
    #pragma unroll
    for (int nt=0; nt<8; nt++) bfr[nt] = *(const bf16x8*)(&Bsl[cur][(nt*16+n0)*32 + q*8]);
    afr[0] = *(const bf16x8*)(&Asl[cur][(w*16+n0)*32 + q*8]);
    afr[1] = *(const bf16x8*)(&Asl[cur][((w+4)*16+n0)*32 + q*8]);
    #pragma unroll
    for (int mi=0; mi<2; mi++)
      #pragma unroll
      for (int nt=0; nt<8; nt++)
        acc[mi][nt] = __builtin_amdgcn_mfma_f32_16x16x32_bf16(afr[mi], bfr[nt], acc[mi][nt], 0,0,0);
    asm volatile("s_waitcnt lgkmcnt(0)" ::: "memory");
    __builtin_amdgcn_s_barrier();
  }
  // epilogue: lane (q,n0) packs rows {4q,4q+1}->qpair 2q (ox) and {4q+2,4q+3}->qpair 2q+1 (oy);
  // 8 tt words are 32B contiguous -> 2x dwordx4 per qpair.
  char* preB = ws + OFF_PRE + (size_t)dir*67108864;
  #pragma unroll
  for (int mi=0; mi<2; mi++){
    int t = tp*2 + mi;
    size_t base = ((size_t)t*4 + w)*32768 + (size_t)nc*512 + (size_t)n0*32;
    uint32 ox[8], oy[8];
    #pragma unroll
    for (int nt=0; nt<8; nt++){
      v4f a = acc[mi][nt];
      ox[nt] = bf16r(a[0]+bv[nt]) | (bf16r(a[1]+bv[nt])<<16);
      oy[nt] = bf16r(a[2]+bv[nt]) | (bf16r(a[3]+bv[nt])<<16);
    }
    char* p0 = preB + base + (size_t)(2*q)*4096;
    *(uint4*)(p0)             = *(uint4*)&ox[0];
    *(uint4*)(p0 + 16)        = *(uint4*)&ox[4];
    *(uint4*)(p0 + 4096)      = *(uint4*)&oy[0];
    *(uint4*)(p0 + 4096 + 16) = *(uint4*)&oy[4];
  }
}

// ---------------- recurrence: R5 structure + setprio MFMA bursts + hoisted polls --------
// grid 64: [dir(1)][bg(2)][q(3)], block 512 (8 waves), wave w owns units [32w,32w+32)
// waves 0..3 produce h_low (units 0..127) -> ctr[0]; waves 4..7 -> h_high -> ctr[1].
// Prefetch: one contiguous 32B block per act lane (2x dwordx4) thanks to PRE layout.
// NOTE: sync protocol frozen — serialized double poll is the validated form (paired-poll
// and s_barrier variants both failed/hung; do not touch).
#define MFMA_SC(A,B,C) __builtin_amdgcn_mfma_scale_f32_16x16x128_f8f6f4( \
    (A), (B), (C), 0, 0, 0, 0x7F7F7F7F, 0, 0x75757575)

template<int R0>
__device__ __forceinline__ void lstm_loop(
    const char* pp, int sstride, int pbase, int ab,
    const v8i (*Wf)[2], float* scw, int n0, bool act,
    char* hb0, char* hb1, int hb_off, float* hp, int hstride,
    int lane, int hw, volatile int* vc, int* ctrs)
{
  uint32 pr[8];
  #pragma unroll
  for (int tt=0;tt<8;tt++) pr[tt] = 0u;
  if (act){
    v4i p0 = *(const v4i*)(pp + pbase);
    v4i p1 = *(const v4i*)(pp + pbase + 16);
    #pragma unroll
    for (int j=0;j<4;j++){ pr[j] = (uint32)p0[j]; pr[4+j] = (uint32)p1[j]; }
  }
  pp += sstride;
  float c0 = 0.f;
  v4f acc[8];
  #pragma unroll
  for (int tt=0;tt<8;tt++) acc[tt] = (v4f){0.f,0.f,0.f,0.f};
  char* hbr = hb0; char* hbw = hb1;
  int rb = (((lane>>4)&1)*16 + n0)*2 + (lane>>5);   // gate-scratch read base
  #pragma unroll 1
  for (int step=0; step<S_N; step++){
    int need = 4*step;
    // ---- wait both producer groups up front (steady-state: near-free) ----
    while (vc[0] < need) __builtin_amdgcn_s_sleep(1);
    while (vc[1] < need) __builtin_amdgcn_s_sleep(1);
    v8i afr0, afr1;
    { v4i lo = *(const v4i*)(hbr + ab);       v4i hi = *(const v4i*)(hbr + ab + 16);
      afr0 = __builtin_shufflevector(lo,hi,0,1,2,3,4,5,6,7); }
    { v4i lo = *(const v4i*)(hbr + ab + 128); v4i hi = *(const v4i*)(hbr + ab + 144);
      afr1 = __builtin_shufflevector(lo,hi,0,1,2,3,4,5,6,7); }
    if (act){
      #pragma unroll
      for (int tt=0;tt<8;tt++){
        acc[tt][R0]   = __uint_as_float(pr[tt]<<16);
        acc[tt][R0+1] = __uint_as_float(pr[tt] & 0xFFFF0000u);
      }
      // prefetch next step's input pre-activations: one 32B block, 2 loads
      v4i p0 = *(const v4i*)(pp + pbase);
      v4i p1 = *(const v4i*)(pp + pbase + 16);
      #pragma unroll
      for (int j=0;j<4;j++){ pr[j] = (uint32)p0[j]; pr[4+j] = (uint32)p1[j]; }
    }
    pp += sstride;
    // ---- unbroken 16-MFMA burst at raised priority (de-phase waves) ----
    __builtin_amdgcn_s_setprio(1);
    #pragma unroll
    for (int tt=0;tt<8;tt++) acc[tt] = MFMA_SC(afr0, Wf[tt][0], acc[tt]);
    #pragma unroll
    for (int tt=0;tt<8;tt++) acc[tt] = MFMA_SC(afr1, Wf[tt][1], acc[tt]);
    __builtin_amdgcn_s_setprio(0);
    // ---- gates -> per-wave LDS scratch (layout [g][uh][n0][mb]) ----
    if (act){
      #pragma unroll
      for (int tt=0;tt<8;tt++){
        int g = tt>>1, uh = tt&1;
        v2f gp = (v2f){ acc[tt][R0], acc[tt][R0+1] };
        *(v2f*)(scw + ((g*2+uh)*16 + n0)*2) = gp;
      }
    }
    float g0 = scw[rb], g1 = scw[rb+64], g2 = scw[rb+128], g3 = scw[rb+192];
    float si = sigm(g0), sf = sigm(g1);
    float tg = tanh_(g2), so = sigm(g3);
    c0 = sf*c0 + si*tg;
    float h = so * tanh_(c0);
    int pk8 = __builtin_amdgcn_cvt_pk_fp8_f32(h*16.f, 0.f, 0, false);
    hbw[hb_off] = (char)(pk8 & 0xFF);
    *hp = h; hp += hstride;
    if (lane == 0) atomicAdd(&ctrs[hw], 1);
    char* t = hbr; hbr = hbw; hbw = t;
  }
}

__global__ __launch_bounds__(512,2)
void k_lstm(char* __restrict__ ws){
  int bx = blockIdx.x;
  int q = bx&7, bg = (bx>>3)&3, dir = bx>>5;
  int tid = threadIdx.x, lane = tid&63, w = tid>>6;
  int n0 = lane&15, lq = lane>>4;
  __shared__ char hbuf[2][16*272];       // h (fp8 x16), stride 272
  __shared__ float gsc[8][256];          // per-wave [g][uh][n0][mb]
  __shared__ int ctrs[2];
  for (int i=tid; i<2176; i+=512) ((int*)hbuf)[i] = 0;
  if (tid < 2) ctrs[tid] = 0;
  // weights: per (dir,w) 32 KB block, per (tt,kk) 64 lanes x 32 B
  const v8i* wp = (const v8i*)(ws + OFF_WHH + (size_t)(dir*8+w)*32768);
  v8i Wf[8][2];
  #pragma unroll
  for (int tt=0; tt<8; tt++)
    #pragma unroll
    for (int kk=0; kk<2; kk++)
      Wf[tt][kk] = wp[(tt*2+kk)*64 + lane];
  // ---- precomputed step-invariant state ----
  int st0 = dir? (S_N-1) : 0;
  const char* pp = ws + OFF_PRE + (size_t)dir*67108864 + (size_t)(st0*4 + bg)*32768;
  const int sstride = dir? -131072 : 131072;
  int pbase = q*4096 + w*512 + n0*32;    // contiguous 32B per act lane
  int ab = n0*272 + lq*32;               // afr base (bytes) within hbuf half
  float* scw = gsc[w];
  bool act = (lq == (q>>1));
  // per-lane epilogue assignment: mb=lane>>5, uh0=(lane>>4)&1, n0
  int mb = lane>>5, uh0 = (lane>>4)&1;
  int u0 = w*32 + uh0*16 + n0;
  int row = 2*q + mb;                    // batch slot within bg's 16
  int hb_off = row*272 + u0;
  float* hout = (float*)(ws+OFF_H);
  int b = bg*16 + row;
  float* hp = hout + ((size_t)b*S_N + st0)*512 + dir*256 + u0;
  const int hstride = dir? -512 : 512;
  int hw = (w >= 4);
  volatile int* vc = (volatile int*)ctrs;
  __syncthreads();
  if (q & 1)
    lstm_loop<2>(pp, sstride, pbase, ab, Wf, scw, n0, act, hbuf[0], hbuf[1],
                 hb_off, hp, hstride, lane, hw, vc, ctrs);
  else
    lstm_loop<0>(pp, sstride, pbase, ab, Wf, scw, n0, act, hbuf[0], hbuf[1],
                 hb_off, hp, hstride, lane, hw, vc, ctrs);
}

// ---------------- classifier: clfW staged in LDS; 1024 blocks x 32 tokens ----------------
__global__ __launch_bounds__(256)
void k_clf(const char* __restrict__ ws, const float* __restrict__ clfW,
           const float* __restrict__ clfb, float* __restrict__ out){
  __shared__ float Wl[4608];             // [9][512]
  int tid = threadIdx.x;
  #pragma unroll
  for (int i=tid; i<1152; i+=256)
    *(float4*)&Wl[i*4] = *(const float4*)(clfW + i*4);
  __syncthreads();
  int lane = tid & 63, wv = tid >> 6;
  int wid0 = blockIdx.x*32 + wv*8;
  #pragma unroll 1
  for (int i=0; i<8; i++){
    int wid = wid0 + i;
    const float4* h = (const float4*)((const float*)(ws+OFF_H) + (size_t)wid*512);
    float4 h0 = h[lane*2], h1 = h[lane*2+1];
    float a[9];
    #pragma unroll
    for (int t=0;t<9;t++){
      const float4* wp = (const float4*)&Wl[t*512];
      float4 w0 = wp[lane*2], w1 = wp[lane*2+1];
      a[t] = h0.x*w0.x + h0.y*w0.y + h0.z*w0.z + h0.w*w0.w
           + h1.x*w1.x + h1.y*w1.y + h1.z*w1.z + h1.w*w1.w;
    }
    #pragma unroll
    for (int t=0;t<9;t++){
      #pragma unroll
      for (int m=32;m>=1;m>>=1) a[t] += __shfl_xor(a[t], m, 64);
    }
    float val = a[0];
    #pragma unroll
    for (int t=1;t<9;t++) val = (lane==t)? a[t] : val;
    if (lane<9) out[1 + (size_t)wid*9 + lane] = val + clfb[lane];
  }
}

// ---------------- CRF: readlane alpha-broadcast + em prefetch + max-tree ----------------
__global__ __launch_bounds__(64)
void k_crf(const int* __restrict__ labels, const float* __restrict__ start_t,
           const float* __restrict__ end_t, const float* __restrict__ trans,
           float* __restrict__ out){
  int b = blockIdx.x, lane = threadIdx.x;
  const float* em = out + 1 + (size_t)b*S_N*T_N;
  const int* tg = labels + (size_t)b*S_N;
  float scv = 0.f;
  for (int t=lane; t<S_N; t+=64){
    int ct = tg[t];
    float e = em[t*T_N + ct];
    if (t==0) scv += start_t[ct] + e;
    else scv += trans[tg[t-1]*T_N + ct] + e;
  }
  if (lane==0) scv += end_t[tg[S_N-1]];
  #pragma unroll
  for (int m=32;m>=1;m>>=1) scv += __shfl_xor(scv, m, 64);
  int j = (lane<9)? lane : 0;
  float wt[9];
  #pragma unroll
  for (int i=0;i<9;i++) wt[i] = trans[i*T_N + j];
  float alpha = start_t[j] + em[j];
  float emn = em[T_N + j];               // prefetch t=1
  #pragma unroll 1
  for (int t=1;t<S_N;t++){
    float emc = emn;
    int tn = (t+1 < S_N)? (t+1) : (S_N-1);
    emn = em[tn*T_N + j];                // prefetch next step's row (hidden under chain)
    float v[9];
    #pragma unroll
    for (int i=0;i<9;i++){
      float av = rdlane(alpha, i);       // scalar broadcast, no LDS round-trip
      v[i] = av + wt[i];
    }
    // balanced max tree (bit-exact: max is associative) — depth 4 vs 9
    float m01 = fmaxf(v[0],v[1]), m23 = fmaxf(v[2],v[3]);
    float m45 = fmaxf(v[4],v[5]), m67 = fmaxf(v[6],v[7]);
    float mx = fmaxf(fmaxf(fmaxf(m01,m23), fmaxf(m45,m67)), v[8]);
    float ss = 0.f;                      // keep sequential sum (fp order preserved)
    #pragma unroll
    for (int i=0;i<9;i++) ss += __builtin_amdgcn_exp2f(1.4426950408889634f*(v[i]-mx));
    alpha = mx + 0.6931471805599453f*__builtin_amdgcn_logf(ss) + emc;
  }
  float av = (lane<9)? alpha + end_t[j] : -3.4e38f;
  float mx = av;
  #pragma unroll
  for (int m=32;m>=1;m>>=1) mx = fmaxf(mx, __shfl_xor(mx, m, 64));
  float es = (lane<9)? __builtin_amdgcn_exp2f(1.4426950408889634f*(av-mx)) : 0.f;
  #pragma unroll
  for (int m=32;m>=1;m>>=1) es += __shfl_xor(es, m, 64);
  float logZ = mx + 0.6931471805599453f*__builtin_amdgcn_logf(es);
  if (lane==0) atomicAdd(out, logZ - scv);
}

extern "C" void kernel_launch(void* const* d_in, const int* in_sizes, int n_in,
                              void* d_out, int out_size, void* d_ws, size_t ws_size,
                              hipStream_t stream){
  const int* ids      = (const int*)d_in[0];
  const int* labels   = (const int*)d_in[1];
  const float* emb    = (const float*)d_in[3];
  const float* wih_f  = (const float*)d_in[4];
  const float* whh_f  = (const float*)d_in[5];
  const float* bih_f  = (const float*)d_in[6];
  const float* bhh_f  = (const float*)d_in[7];
  const float* wih_b  = (const float*)d_in[8];
  const float* whh_b  = (const float*)d_in[9];
  const float* bih_b  = (const float*)d_in[10];
  const float* bhh_b  = (const float*)d_in[11];
  const float* clfW   = (const float*)d_in[12];
  const float* clfb   = (const float*)d_in[13];
  const float* start_t= (const float*)d_in[14];
  const float* end_t  = (const float*)d_in[15];
  const float* trans  = (const float*)d_in[16];
  float* out = (float*)d_out;
  char* ws = (char*)d_ws;

  hipLaunchKernelGGL(k_prep, dim3((V_N*40 + 2*G_N*40 + 255)/256), dim3(256), 0, stream,
                     emb, wih_f, wih_b, whh_f, whh_b, ws, out);
  hipLaunchKernelGGL(k_gemm1, dim3(4096), dim3(256), 0, stream, ids, ws,
                     bih_f, bhh_f, bih_b, bhh_b);
  hipLaunchKernelGGL(k_lstm, dim3(64), dim3(512), 0, stream, ws);
  hipLaunchKernelGGL(k_clf, dim3(1024), dim3(256), 0, stream, ws, clfW, clfb, out);
  hipLaunchKernelGGL(k_crf, dim3(64), dim3(64), 0, stream, labels, start_t, end_t, trans, out);
}

// Round 12
// 748.943 us; speedup vs baseline: 1.0064x; 1.0064x over previous
//
#include <hip/hip_runtime.h>
#include <stdint.h>

typedef float v4f __attribute__((ext_vector_type(4)));
typedef float v2f __attribute__((ext_vector_type(2)));
typedef short bf16x8 __attribute__((ext_vector_type(8)));
typedef int v4i __attribute__((ext_vector_type(4)));
typedef int v8i __attribute__((ext_vector_type(8)));
typedef unsigned int uint32;
typedef unsigned long long u64;

#define V_N 30000
#define E_N 300
#define EPAD 320
#define H_N 256
#define G_N 1024
#define B_N 64
#define S_N 512
#define T_N 9

// workspace layout (bytes)
#define OFF_EMB  ((size_t)0)            // [V][320] bf16          19,200,000
#define OFF_WIH  ((size_t)19200000)     // [2][1024][320] bf16     1,310,720
#define OFF_WHH  ((size_t)20510720)     // [2][8][8][2][64][32B]     524,288
#define OFF_PRE  ((size_t)21035008)     // [2][t512][bg4][qp8][w8][n16][tt8]4B = 134,217,728
#define OFF_H    ((size_t)155252736)    // [64][512][512] f32      67,108,864

__device__ __forceinline__ uint32 bf16r(float x){
  uint32 u = __float_as_uint(x);
  u += 0x7FFFu + ((u>>16)&1u);
  return u>>16;
}
__device__ __forceinline__ float sigm(float x){
  return __builtin_amdgcn_rcpf(1.f + __builtin_amdgcn_exp2f(-1.4426950408889634f*x));
}
__device__ __forceinline__ float tanh_(float x){
  return 1.f - 2.f*__builtin_amdgcn_rcpf(1.f + __builtin_amdgcn_exp2f(2.8853900817779268f*x));
}
__device__ __forceinline__ void gld16(const void* g, void* l){
  __builtin_amdgcn_global_load_lds(
    (const __attribute__((address_space(1))) void*)g,
    (__attribute__((address_space(3))) void*)l, 16, 0, 0);
}
__device__ __forceinline__ float rdlane(float x, int l){
  return __uint_as_float(__builtin_amdgcn_readlane(__float_as_uint(x), l));
}

// ---------------- prep (fused): out[0]=0, emb+Wih -> bf16 pad320, Whh -> fp8 ----------------
__global__ void k_prep(const float* __restrict__ emb,
                       const float* __restrict__ wih_f,
                       const float* __restrict__ wih_b,
                       const float* __restrict__ whh_f,
                       const float* __restrict__ whh_b,
                       char* __restrict__ ws,
                       float* __restrict__ out){
  int tid = blockIdx.x*256 + threadIdx.x;
  if (tid == 0) out[0] = 0.f;
  // ---- Whh -> fp8 e4m3 (x64) in 16x16x128 B-operand layout (first 65536 threads) ----
  if (tid < 65536){
    int part = tid&3;
    int lane = (tid>>2)&63;
    int kk = (tid>>8)&1, tt = (tid>>9)&7, w = (tid>>12)&7, dir = (tid>>15)&1;
    const float* W = dir? whh_b : whh_f;
    int n = lane&15, lq = lane>>4;
    int col = (tt>>1)*256 + w*32 + (tt&1)*16 + n;   // gate*256 + unit
    int k0  = kk*128 + lq*32 + part*8;
    const float* p = W + (size_t)col*H_N + k0;
    int lo = __builtin_amdgcn_cvt_pk_fp8_f32(p[0]*64.f, p[1]*64.f, 0, false);
    lo = __builtin_amdgcn_cvt_pk_fp8_f32(p[2]*64.f, p[3]*64.f, lo, true);
    int hi = __builtin_amdgcn_cvt_pk_fp8_f32(p[4]*64.f, p[5]*64.f, 0, false);
    hi = __builtin_amdgcn_cvt_pk_fp8_f32(p[6]*64.f, p[7]*64.f, hi, true);
    u64 v = (uint32)lo | ((u64)(uint32)hi<<32);
    ((u64*)(ws+OFF_WHH))[tid] = v;
  }
  // ---- emb + Wih -> bf16 padded to K=320 ----
  const int NE = V_N*40;
  unsigned short* eo = (unsigned short*)(ws + OFF_EMB);
  unsigned short* wo = (unsigned short*)(ws + OFF_WIH);
  const float* src; unsigned short* dst; int g;
  if (tid < NE){
    int row = tid/40; g = tid%40;
    src = emb + (size_t)row*E_N;
    dst = eo + (size_t)row*EPAD + g*8;
  } else if (tid < NE + 2*G_N*40){
    int t2 = tid - NE;
    int dir = t2/(G_N*40); int r2 = t2%(G_N*40);
    int row = r2/40; g = r2%40;
    src = (dir? wih_b : wih_f) + (size_t)row*E_N;
    dst = wo + ((size_t)dir*G_N + row)*EPAD + g*8;
  } else return;
  unsigned short v[8];
  #pragma unroll
  for (int j=0;j<8;j++){
    int c = g*8+j;
    float x = (c < E_N)? src[c] : 0.f;
    v[j] = (unsigned short)bf16r(x);
  }
  uint4 pk;
  pk.x = (uint32)v[0] | ((uint32)v[1]<<16);
  pk.y = (uint32)v[2] | ((uint32)v[3]<<16);
  pk.z = (uint32)v[4] | ((uint32)v[5]<<16);
  pk.w = (uint32)v[6] | ((uint32)v[7]<<16);
  *(uint4*)dst = pk;
}

// ---------------- input projection: pre = emb[ids] @ Wih^T + bias (bf16 MFMA) -------------
// Triple-buffered global_load_lds staging, 2-deep prefetch (loads span 2 iterations,
// counted vmcnt(8) retires only the 2-iter-old batch); raw s_barrier (no vmcnt drain).
// Block nc covers lstm w_l = nc: B rows c(r) = (r>>5)*256 + nc*32 + (r&31) so tile nt == tt.
// Epilogue: each lane stores 32B-contiguous tt runs -> 256B-coalesced segments per q-group.
__global__ __launch_bounds__(256,2)
void k_gemm1(const int* __restrict__ ids, char* __restrict__ ws,
             const float* __restrict__ bih_f, const float* __restrict__ bhh_f,
             const float* __restrict__ bih_b, const float* __restrict__ bhh_b){
  int bx = blockIdx.x;                      // [dir(2)][tp(256)][nc(8)]
  int nc = bx & 7, tp = (bx>>3)&255, dir = bx>>11;
  const char* embB = (const char*)(ws+OFF_EMB);
  const char* wihB = (const char*)(ws+OFF_WIH) + (size_t)dir*G_N*EPAD*2;
  __shared__ unsigned short Asl[3][128*32];
  __shared__ unsigned short Bsl[3][128*32];
  __shared__ int ids_s[128];
  int tid = threadIdx.x, lane = tid&63, w = tid>>6;
  if (tid < 128){
    int t = tp*2 + (tid>>6), b = tid&63;
    ids_s[tid] = ids[b*S_N + t];
  }
  __syncthreads();
  v4f acc[2][8];
  #pragma unroll
  for (int i=0;i<2;i++)
    #pragma unroll
    for (int j=0;j<8;j++) acc[i][j] = (v4f){0.f,0.f,0.f,0.f};
  int n0 = lane&15, q = lane>>4;
  // per-wave staging rows: wave w covers local row blocks [w*16,..) and [(w+4)*16,..)
  int rA0 = w*16 + (lane>>2), rA1 = (w+4)*16 + (lane>>2);
  int ch = (lane&3)*16;                      // byte chunk within a 64B row-slice
  long idA0 = ids_s[rA0], idA1 = ids_s[rA1];
  const char* gA0 = embB + idA0*640 + ch;
  const char* gA1 = embB + idA1*640 + ch;
  // B local row r -> global unit row c(r) = (r>>5)*256 + nc*32 + (r&31)
  int cB0 = ((rA0>>5)<<8) + nc*32 + (rA0&31);
  int cB1 = ((rA1>>5)<<8) + nc*32 + (rA1&31);
  const char* gB0 = wihB + (size_t)cB0*640 + ch;
  const char* gB1 = wihB + (size_t)cB1*640 + ch;
  const float* bi = dir? bih_b : bih_f;
  const float* bh = dir? bhh_b : bhh_f;
  float bv[8];
  #pragma unroll
  for (int nt=0; nt<8; nt++){
    int c = ((nt>>1)<<8) + nc*32 + ((nt&1)<<4) + n0;   // unit col for tile nt (== tt)
    bv[nt] = bi[c] + bh[c];
  }
  // drain bias/ids loads so loop vmcnt counting is exact
  asm volatile("s_waitcnt vmcnt(0)" ::: "memory");
  // prologue stage: ks=0 -> buf0, ks=1 -> buf1
  {
    gld16(gA0,      (char*)Asl[0] + (size_t)w*1024);
    gld16(gA1,      (char*)Asl[0] + (size_t)(w+4)*1024);
    gld16(gB0,      (char*)Bsl[0] + (size_t)w*1024);
    gld16(gB1,      (char*)Bsl[0] + (size_t)(w+4)*1024);
    gld16(gA0 + 64, (char*)Asl[1] + (size_t)w*1024);
    gld16(gA1 + 64, (char*)Asl[1] + (size_t)(w+4)*1024);
    gld16(gB0 + 64, (char*)Bsl[1] + (size_t)w*1024);
    gld16(gB1 + 64, (char*)Bsl[1] + (size_t)(w+4)*1024);
  }
  for (int ks=0; ks<10; ks++){
    int cur = ks%3;
    if (ks < 8){
      int nb = (ks+2)%3;
      int ko = (ks+2)*64;
      gld16(gA0 + ko, (char*)Asl[nb] + (size_t)w*1024);
      gld16(gA1 + ko, (char*)Asl[nb] + (size_t)(w+4)*1024);
      gld16(gB0 + ko, (char*)Bsl[nb] + (size_t)w*1024);
      gld16(gB1 + ko, (char*)Bsl[nb] + (size_t)(w+4)*1024);
      asm volatile("s_waitcnt vmcnt(8)" ::: "memory");   // retire the 2-iter-old batch
    } else if (ks == 8){
      asm volatile("s_waitcnt vmcnt(4)" ::: "memory");
    } else {
      asm volatile("s_waitcnt vmcnt(0)" ::: "memory");
    }
    __builtin_amdgcn_s_barrier();
    bf16x8 bfr[8], afr[2];
    #pragma unroll
    for (int nt=0; nt<8; nt++) bfr[nt] = *(const bf16x8*)(&Bsl[cur][(nt*16+n0)*32 + q*8]);
    afr[0] = *(const bf16x8*)(&Asl[cur][(w*16+n0)*32 + q*8]);
    afr[1] = *(const bf16x8*)(&Asl[cur][((w+4)*16+n0)*32 + q*8]);
    #pragma unroll
    for (int mi=0; mi<2; mi++)
      #pragma unroll
      for (int nt=0; nt<8; nt++)
        acc[mi][nt] = __builtin_amdgcn_mfma_f32_16x16x32_bf16(afr[mi], bfr[nt], acc[mi][nt], 0,0,0);
    asm volatile("s_waitcnt lgkmcnt(0)" ::: "memory");
    __builtin_amdgcn_s_barrier();
  }
  // epilogue: lane (q,n0) packs rows {4q,4q+1}->qpair 2q (ox) and {4q+2,4q+3}->qpair 2q+1 (oy);
  // 8 tt words are 32B contiguous -> 2x dwordx4 per qpair.
  char* preB = ws + OFF_PRE + (size_t)dir*67108864;
  #pragma unroll
  for (int mi=0; mi<2; mi++){
    int t = tp*2 + mi;
    size_t base = ((size_t)t*4 + w)*32768 + (size_t)nc*512 + (size_t)n0*32;
    uint32 ox[8], oy[8];
    #pragma unroll
    for (int nt=0; nt<8; nt++){
      v4f a = acc[mi][nt];
      ox[nt] = bf16r(a[0]+bv[nt]) | (bf16r(a[1]+bv[nt])<<16);
      oy[nt] = bf16r(a[2]+bv[nt]) | (bf16r(a[3]+bv[nt])<<16);
    }
    char* p0 = preB + base + (size_t)(2*q)*4096;
    *(uint4*)(p0)             = *(uint4*)&ox[0];
    *(uint4*)(p0 + 16)        = *(uint4*)&ox[4];
    *(uint4*)(p0 + 4096)      = *(uint4*)&oy[0];
    *(uint4*)(p0 + 4096 + 16) = *(uint4*)&oy[4];
  }
}

// ---------------- recurrence: R5 structure + setprio MFMA bursts + hoisted polls --------
// grid 64: [dir(1)][bg(2)][q(3)], block 512 (8 waves), wave w owns units [32w,32w+32)
// waves 0..3 produce h_low (units 0..127) -> ctr[0]; waves 4..7 -> h_high -> ctr[1].
// Prefetch: one contiguous 32B block per act lane (2x dwordx4) thanks to PRE layout.
// NOTE: sync protocol frozen — serialized double poll is the validated form (paired-poll
// and s_barrier variants both failed/hung; do not touch).
#define MFMA_SC(A,B,C) __builtin_amdgcn_mfma_scale_f32_16x16x128_f8f6f4( \
    (A), (B), (C), 0, 0, 0, 0x7F7F7F7F, 0, 0x75757575)

template<int R0>
__device__ __forceinline__ void lstm_loop(
    const char* pp, int sstride, int pbase, int ab,
    const v8i (*Wf)[2], float* scw, int n0, bool act,
    char* hb0, char* hb1, int hb_off, float* hp, int hstride,
    int lane, int hw, volatile int* vc, int* ctrs)
{
  uint32 pr[8];
  #pragma unroll
  for (int tt=0;tt<8;tt++) pr[tt] = 0u;
  if (act){
    v4i p0 = *(const v4i*)(pp + pbase);
    v4i p1 = *(const v4i*)(pp + pbase + 16);
    #pragma unroll
    for (int j=0;j<4;j++){ pr[j] = (uint32)p0[j]; pr[4+j] = (uint32)p1[j]; }
  }
  pp += sstride;
  float c0 = 0.f;
  v4f acc[8];
  #pragma unroll
  for (int tt=0;tt<8;tt++) acc[tt] = (v4f){0.f,0.f,0.f,0.f};
  char* hbr = hb0; char* hbw = hb1;
  int rb = (((lane>>4)&1)*16 + n0)*2 + (lane>>5);   // gate-scratch read base
  #pragma unroll 1
  for (int step=0; step<S_N; step++){
    int need = 4*step;
    // ---- wait both producer groups up front (steady-state: near-free) ----
    while (vc[0] < need) __builtin_amdgcn_s_sleep(1);
    while (vc[1] < need) __builtin_amdgcn_s_sleep(1);
    v8i afr0, afr1;
    { v4i lo = *(const v4i*)(hbr + ab);       v4i hi = *(const v4i*)(hbr + ab + 16);
      afr0 = __builtin_shufflevector(lo,hi,0,1,2,3,4,5,6,7); }
    { v4i lo = *(const v4i*)(hbr + ab + 128); v4i hi = *(const v4i*)(hbr + ab + 144);
      afr1 = __builtin_shufflevector(lo,hi,0,1,2,3,4,5,6,7); }
    if (act){
      #pragma unroll
      for (int tt=0;tt<8;tt++){
        acc[tt][R0]   = __uint_as_float(pr[tt]<<16);
        acc[tt][R0+1] = __uint_as_float(pr[tt] & 0xFFFF0000u);
      }
      // prefetch next step's input pre-activations: one 32B block, 2 loads
      v4i p0 = *(const v4i*)(pp + pbase);
      v4i p1 = *(const v4i*)(pp + pbase + 16);
      #pragma unroll
      for (int j=0;j<4;j++){ pr[j] = (uint32)p0[j]; pr[4+j] = (uint32)p1[j]; }
    }
    pp += sstride;
    // ---- unbroken 16-MFMA burst at raised priority (de-phase waves) ----
    __builtin_amdgcn_s_setprio(1);
    #pragma unroll
    for (int tt=0;tt<8;tt++) acc[tt] = MFMA_SC(afr0, Wf[tt][0], acc[tt]);
    #pragma unroll
    for (int tt=0;tt<8;tt++) acc[tt] = MFMA_SC(afr1, Wf[tt][1], acc[tt]);
    __builtin_amdgcn_s_setprio(0);
    // ---- gates -> per-wave LDS scratch (layout [g][uh][n0][mb]) ----
    if (act){
      #pragma unroll
      for (int tt=0;tt<8;tt++){
        int g = tt>>1, uh = tt&1;
        v2f gp = (v2f){ acc[tt][R0], acc[tt][R0+1] };
        *(v2f*)(scw + ((g*2+uh)*16 + n0)*2) = gp;
      }
    }
    float g0 = scw[rb], g1 = scw[rb+64], g2 = scw[rb+128], g3 = scw[rb+192];
    float si = sigm(g0), sf = sigm(g1);
    float tg = tanh_(g2), so = sigm(g3);
    c0 = sf*c0 + si*tg;
    float h = so * tanh_(c0);
    int pk8 = __builtin_amdgcn_cvt_pk_fp8_f32(h*16.f, 0.f, 0, false);
    hbw[hb_off] = (char)(pk8 & 0xFF);
    *hp = h; hp += hstride;
    if (lane == 0) atomicAdd(&ctrs[hw], 1);
    char* t = hbr; hbr = hbw; hbw = t;
  }
}

__global__ __launch_bounds__(512,2)
void k_lstm(char* __restrict__ ws){
  int bx = blockIdx.x;
  int q = bx&7, bg = (bx>>3)&3, dir = bx>>5;
  int tid = threadIdx.x, lane = tid&63, w = tid>>6;
  int n0 = lane&15, lq = lane>>4;
  __shared__ char hbuf[2][16*272];       // h (fp8 x16), stride 272
  __shared__ float gsc[8][256];          // per-wave [g][uh][n0][mb]
  __shared__ int ctrs[2];
  for (int i=tid; i<2176; i+=512) ((int*)hbuf)[i] = 0;
  if (tid < 2) ctrs[tid] = 0;
  // weights: per (dir,w) 32 KB block, per (tt,kk) 64 lanes x 32 B
  const v8i* wp = (const v8i*)(ws + OFF_WHH + (size_t)(dir*8+w)*32768);
  v8i Wf[8][2];
  #pragma unroll
  for (int tt=0; tt<8; tt++)
    #pragma unroll
    for (int kk=0; kk<2; kk++)
      Wf[tt][kk] = wp[(tt*2+kk)*64 + lane];
  // ---- precomputed step-invariant state ----
  int st0 = dir? (S_N-1) : 0;
  const char* pp = ws + OFF_PRE + (size_t)dir*67108864 + (size_t)(st0*4 + bg)*32768;
  const int sstride = dir? -131072 : 131072;
  int pbase = q*4096 + w*512 + n0*32;    // contiguous 32B per act lane
  int ab = n0*272 + lq*32;               // afr base (bytes) within hbuf half
  float* scw = gsc[w];
  bool act = (lq == (q>>1));
  // per-lane epilogue assignment: mb=lane>>5, uh0=(lane>>4)&1, n0
  int mb = lane>>5, uh0 = (lane>>4)&1;
  int u0 = w*32 + uh0*16 + n0;
  int row = 2*q + mb;                    // batch slot within bg's 16
  int hb_off = row*272 + u0;
  float* hout = (float*)(ws+OFF_H);
  int b = bg*16 + row;
  float* hp = hout + ((size_t)b*S_N + st0)*512 + dir*256 + u0;
  const int hstride = dir? -512 : 512;
  int hw = (w >= 4);
  volatile int* vc = (volatile int*)ctrs;
  __syncthreads();
  if (q & 1)
    lstm_loop<2>(pp, sstride, pbase, ab, Wf, scw, n0, act, hbuf[0], hbuf[1],
                 hb_off, hp, hstride, lane, hw, vc, ctrs);
  else
    lstm_loop<0>(pp, sstride, pbase, ab, Wf, scw, n0, act, hbuf[0], hbuf[1],
                 hb_off, hp, hstride, lane, hw, vc, ctrs);
}

// ---------------- classifier: clfW staged in LDS; 1024 blocks x 32 tokens ----------------
__global__ __launch_bounds__(256)
void k_clf(const char* __restrict__ ws, const float* __restrict__ clfW,
           const float* __restrict__ clfb, float* __restrict__ out){
  __shared__ float Wl[4608];             // [9][512]
  int tid = threadIdx.x;
  #pragma unroll
  for (int i=tid; i<1152; i+=256)
    *(float4*)&Wl[i*4] = *(const float4*)(clfW + i*4);
  __syncthreads();
  int lane = tid & 63, wv = tid >> 6;
  int wid0 = blockIdx.x*32 + wv*8;
  #pragma unroll 1
  for (int i=0; i<8; i++){
    int wid = wid0 + i;
    const float4* h = (const float4*)((const float*)(ws+OFF_H) + (size_t)wid*512);
    float4 h0 = h[lane*2], h1 = h[lane*2+1];
    float a[9];
    #pragma unroll
    for (int t=0;t<9;t++){
      const float4* wp = (const float4*)&Wl[t*512];
      float4 w0 = wp[lane*2], w1 = wp[lane*2+1];
      a[t] = h0.x*w0.x + h0.y*w0.y + h0.z*w0.z + h0.w*w0.w
           + h1.x*w1.x + h1.y*w1.y + h1.z*w1.z + h1.w*w1.w;
    }
    #pragma unroll
    for (int t=0;t<9;t++){
      #pragma unroll
      for (int m=32;m>=1;m>>=1) a[t] += __shfl_xor(a[t], m, 64);
    }
    float val = a[0];
    #pragma unroll
    for (int t=1;t<9;t++) val = (lane==t)? a[t] : val;
    if (lane<9) out[1 + (size_t)wid*9 + lane] = val + clfb[lane];
  }
}

// ---------------- CRF: readlane alpha-broadcast + em prefetch + max-tree ----------------
__global__ __launch_bounds__(64)
void k_crf(const int* __restrict__ labels, const float* __restrict__ start_t,
           const float* __restrict__ end_t, const float* __restrict__ trans,
           float* __restrict__ out){
  int b = blockIdx.x, lane = threadIdx.x;
  const float* em = out + 1 + (size_t)b*S_N*T_N;
  const int* tg = labels + (size_t)b*S_N;
  float scv = 0.f;
  for (int t=lane; t<S_N; t+=64){
    int ct = tg[t];
    float e = em[t*T_N + ct];
    if (t==0) scv += start_t[ct] + e;
    else scv += trans[tg[t-1]*T_N + ct] + e;
  }
  if (lane==0) scv += end_t[tg[S_N-1]];
  #pragma unroll
  for (int m=32;m>=1;m>>=1) scv += __shfl_xor(scv, m, 64);
  int j = (lane<9)? lane : 0;
  float wt[9];
  #pragma unroll
  for (int i=0;i<9;i++) wt[i] = trans[i*T_N + j];
  float alpha = start_t[j] + em[j];
  float emn = em[T_N + j];               // prefetch t=1
  #pragma unroll 1
  for (int t=1;t<S_N;t++){
    float emc = emn;
    int tn = (t+1 < S_N)? (t+1) : (S_N-1);
    emn = em[tn*T_N + j];                // prefetch next step's row (hidden under chain)
    float v[9];
    #pragma unroll
    for (int i=0;i<9;i++){
      float av = rdlane(alpha, i);       // scalar broadcast, no LDS round-trip
      v[i] = av + wt[i];
    }
    // balanced max tree (bit-exact: max is associative) — depth 4 vs 9
    float m01 = fmaxf(v[0],v[1]), m23 = fmaxf(v[2],v[3]);
    float m45 = fmaxf(v[4],v[5]), m67 = fmaxf(v[6],v[7]);
    float mx = fmaxf(fmaxf(fmaxf(m01,m23), fmaxf(m45,m67)), v[8]);
    float ss = 0.f;                      // keep sequential sum (fp order preserved)
    #pragma unroll
    for (int i=0;i<9;i++) ss += __builtin_amdgcn_exp2f(1.4426950408889634f*(v[i]-mx));
    alpha = mx + 0.6931471805599453f*__builtin_amdgcn_logf(ss) + emc;
  }
  float av = (lane<9)? alpha + end_t[j] : -3.4e38f;
  float mx = av;
  #pragma unroll
  for (int m=32;m>=1;m>>=1) mx = fmaxf(mx, __shfl_xor(mx, m, 64));
  float es = (lane<9)? __builtin_amdgcn_exp2f(1.4426950408889634f*(av-mx)) : 0.f;
  #pragma unroll
  for (int m=32;m>=1;m>>=1) es += __shfl_xor(es, m, 64);
  float logZ = mx + 0.6931471805599453f*__builtin_amdgcn_logf(es);
  if (lane==0) atomicAdd(out, logZ - scv);
}

extern "C" void kernel_launch(void* const* d_in, const int* in_sizes, int n_in,
                              void* d_out, int out_size, void* d_ws, size_t ws_size,
                              hipStream_t stream){
  const int* ids      = (const int*)d_in[0];
  const int* labels   = (const int*)d_in[1];
  const float* emb    = (const float*)d_in[3];
  const float* wih_f  = (const float*)d_in[4];
  const float* whh_f  = (const float*)d_in[5];
  const float* bih_f  = (const float*)d_in[6];
  const float* bhh_f  = (const float*)d_in[7];
  const float* wih_b  = (const float*)d_in[8];
  const float* whh_b  = (const float*)d_in[9];
  const float* bih_b  = (const float*)d_in[10];
  const float* bhh_b  = (const float*)d_in[11];
  const float* clfW   = (const float*)d_in[12];
  const float* clfb   = (const float*)d_in[13];
  const float* start_t= (const float*)d_in[14];
  const float* end_t  = (const float*)d_in[15];
  const float* trans  = (const float*)d_in[16];
  float* out = (float*)d_out;
  char* ws = (char*)d_ws;

  hipLaunchKernelGGL(k_prep, dim3((V_N*40 + 2*G_N*40 + 255)/256), dim3(256), 0, stream,
                     emb, wih_f, wih_b, whh_f, whh_b, ws, out);
  hipLaunchKernelGGL(k_gemm1, dim3(4096), dim3(256), 0, stream, ids, ws,
                     bih_f, bhh_f, bih_b, bhh_b);
  hipLaunchKernelGGL(k_lstm, dim3(64), dim3(512), 0, stream, ws);
  hipLaunchKernelGGL(k_clf, dim3(1024), dim3(256), 0, stream, ws, clfW, clfb, out);
  hipLaunchKernelGGL(k_crf, dim3(64), dim3(64), 0, stream, labels, start_t, end_t, trans, out);
}